// Round 5
// baseline (424.180 us; speedup 1.0000x reference)
//
#include <hip/hip_runtime.h>
#include <hip/hip_bf16.h>

// SkipGRU: B=64, T=4096, F=128, U=128, P=16 -> 1024 chains of length 256.
// Phase-split:
//   prep   : pack Wk into MFMA B-fragment layout (f16) + combined x-side bias.
//   phase1 : xm = x @ Wk + b for all B*T rows, f16, full chip (HBM-bound).
//   phase2 : recurrence on 64 WGs; per step only the h-GEMM (12 MFMAs/wave),
//            accumulators C-initialized from prefetched xm f16 loads.
// Falls back to the round-4 monolithic kernel if ws_size is too small.

#define B_N 64
#define T_N 4096
#define F_N 128
#define U_N 128
#define P_N 16
#define L_N 256
#define NW 8
#define NT (NW * 64)   // 512 threads (phase2)

#define XM_BYTES  (64ULL * 4096 * 384 * 2)        // 201326592
#define WKF_OFF   XM_BYTES                         // 49152 f16 = 98304 B
#define WKF_ELEMS (24 * 4 * 64 * 8)
#define BC_OFF    (WKF_OFF + (size_t)WKF_ELEMS * 2)
#define WS_NEED   (BC_OFF + 384 * 4)

typedef _Float16 f16x8 __attribute__((ext_vector_type(8)));
typedef _Float16 f16x4 __attribute__((ext_vector_type(4)));
typedef float f32x4 __attribute__((ext_vector_type(4)));

__device__ __forceinline__ float sigmoidf_(float x) {
    return __builtin_amdgcn_rcpf(1.0f + __expf(-x));
}

// Position of logical k within a fragment-contiguous row:
// row[kt*32 + lg*8 + e] holds k = kt*32 + 16*(e>>2) + 4*lg + (e&3).
__device__ __forceinline__ int fpos(int k) {
    return ((k >> 5) << 5) + (((k >> 2) & 3) << 3) + (((k >> 4) & 1) << 2) + (k & 3);
}

// barrier with LDS-only drain; global loads/stores stay in flight
#define BAR() do { \
    asm volatile("s_waitcnt lgkmcnt(0)" ::: "memory"); \
    __builtin_amdgcn_s_barrier(); \
    __builtin_amdgcn_sched_barrier(0); \
} while (0)

// ---------------------------------------------------------------- prep ----
__global__ void prep_kernel(const float* __restrict__ Wk,
                            const float* __restrict__ bias,
                            _Float16* __restrict__ wkf,
                            float* __restrict__ bc)
{
    int q = blockIdx.x * 256 + threadIdx.x;
    if (q < WKF_ELEMS) {
        int e = q & 7, lane = (q >> 3) & 63, kt = (q >> 9) & 3, n = q >> 11;
        int lg = lane >> 4, ln = lane & 15;
        int k = kt * 32 + ((e >> 2) << 4) + (lg << 2) + (e & 3);
        wkf[q] = (_Float16)Wk[(size_t)k * 384 + n * 16 + ln];
    }
    if (q < 384)   // combined x-side bias: z/r add recurrent bias; h input-only
        bc[q] = bias[q] + (q < 256 ? bias[384 + q] : 0.0f);
}

// -------------------------------------------------------------- phase 1 ---
// 2048 WGs x 256 threads; each WG computes 128 rows of xm (f16).
__global__ __launch_bounds__(256, 1) void phase1_kernel(
    const float* __restrict__ xg, const _Float16* __restrict__ wkf,
    const float* __restrict__ bc, _Float16* __restrict__ xm)
{
    __shared__ __align__(16) _Float16 A[128][132];     // frag-contig x rows
    __shared__ __align__(16) _Float16 BF[WKF_ELEMS];   // Wk fragments

    const int tid = threadIdx.x, lane = tid & 63, wave = tid >> 6;
    const int ln = lane & 15, lg = lane >> 4;
    const size_t row0 = (size_t)blockIdx.x * 128;

    for (int q = tid; q < WKF_ELEMS / 4; q += 256)     // coalesced 8B copies
        ((ushort4*)BF)[q] = ((const ushort4*)wkf)[q];
    for (int q = tid; q < 4096; q += 256) {
        int r = q >> 5, c = (q & 31) << 2;
        float4 v = *(const float4*)(xg + (row0 + r) * F_N + c);
        f16x4 h = {(_Float16)v.x, (_Float16)v.y, (_Float16)v.z, (_Float16)v.w};
        *(f16x4*)&A[r][fpos(c)] = h;
    }
    __syncthreads();

    f16x8 af[2][4];
    #pragma unroll
    for (int i = 0; i < 2; ++i)
        #pragma unroll
        for (int kt = 0; kt < 4; ++kt)
            af[i][kt] = *(const f16x8*)&A[(2 * wave + i) * 16 + ln][kt * 32 + lg * 8];

    for (int n = 0; n < 24; ++n) {
        f16x8 bf[4];
        #pragma unroll
        for (int kt = 0; kt < 4; ++kt)
            bf[kt] = *(const f16x8*)&BF[(((n * 4 + kt) * 64 + lane) << 3)];
        float bcn = bc[n * 16 + ln];
        #pragma unroll
        for (int i = 0; i < 2; ++i) {
            f32x4 acc = {bcn, bcn, bcn, bcn};
            #pragma unroll
            for (int kt = 0; kt < 4; ++kt)
                acc = __builtin_amdgcn_mfma_f32_16x16x32_f16(af[i][kt], bf[kt], acc, 0, 0, 0);
            _Float16* op = xm + (row0 + (2 * wave + i) * 16 + lg * 4) * 384 + n * 16 + ln;
            #pragma unroll
            for (int e = 0; e < 4; ++e) op[(size_t)e * 384] = (_Float16)acc[e];
        }
    }
}

// -------------------------------------------------------------- phase 2 ---
struct XmSet { _Float16 z0,z1,z2,z3, r0,r1,r2,r3, h0,h1,h2,h3; };
#define LOAD_XM(S, l) do { const _Float16* _p = xmlane + (size_t)(l) * 6144; \
    S.z0=_p[0];   S.z1=_p[384];  S.z2=_p[768];  S.z3=_p[1152]; \
    S.r0=_p[128]; S.r1=_p[512];  S.r2=_p[896];  S.r3=_p[1280]; \
    S.h0=_p[256]; S.h1=_p[640];  S.h2=_p[1024]; S.h3=_p[1408]; } while (0)

__global__ __launch_bounds__(NT, 2) void phase2_kernel(
    const float* __restrict__ Wr, const float* __restrict__ bias,
    const _Float16* __restrict__ xm, float* __restrict__ out)
{
    __shared__ __align__(16) _Float16 A_h[2][16][132];

    const int tid  = threadIdx.x;
    const int lane = tid & 63;
    const int wave = tid >> 6;
    const int ln   = lane & 15;
    const int lg   = lane >> 4;
    const int u    = wave * 16 + ln;
    const int m0   = lg * 4;
    const int b    = blockIdx.x;
    const int hcol = fpos(u);

    const float brh = bias[384 + 256 + u];   // recurrent h-gate bias (not folded)

    // recurrent weight fragments (z/r/h), k-map = fpos inverse
    f16x8 wzr[4], wrr[4], whr[4];
    #pragma unroll
    for (int kt = 0; kt < 4; ++kt) {
        #pragma unroll
        for (int e = 0; e < 8; ++e) {
            int k = kt * 32 + ((e >> 2) << 4) + (lg << 2) + (e & 3);
            const float* wrp = Wr + (size_t)k * 384;
            wzr[kt][e] = (_Float16)wrp[u];
            wrr[kt][e] = (_Float16)wrp[128 + u];
            whr[kt][e] = (_Float16)wrp[256 + u];
        }
    }

    for (int q = tid; q < 16 * 132; q += NT) ((_Float16*)A_h[0])[q] = (_Float16)0;

    const _Float16* xmlane = xm + ((size_t)b * T_N + m0) * 384 + u;
    XmSet SA, SB;
    LOAD_XM(SA, 0);
    LOAD_XM(SB, 1);

    f32x4 hreg = {0.f, 0.f, 0.f, 0.f};
    float* op = out + ((size_t)b * T_N + m0) * U_N + u;
    __syncthreads();

    auto step = [&](int l, XmSet& S) {
        const int rbuf = l & 1, wbuf = (l + 1) & 1;
        f16x8 ahf[4];
        #pragma unroll
        for (int kt = 0; kt < 4; ++kt)
            ahf[kt] = *(const f16x8*)&A_h[rbuf][ln][kt * 32 + lg * 8];
        // C-init from xm (biases pre-folded in phase1); brh for the hh chain
        f32x4 az  = {(float)S.z0, (float)S.z1, (float)S.z2, (float)S.z3};
        f32x4 ar  = {(float)S.r0, (float)S.r1, (float)S.r2, (float)S.r3};
        f32x4 ahh = {brh, brh, brh, brh};
        float xh0 = (float)S.h0, xh1 = (float)S.h1, xh2 = (float)S.h2, xh3 = (float)S.h3;
        #pragma unroll
        for (int kt = 0; kt < 4; ++kt) {
            az  = __builtin_amdgcn_mfma_f32_16x16x32_f16(ahf[kt], wzr[kt], az, 0, 0, 0);
            ar  = __builtin_amdgcn_mfma_f32_16x16x32_f16(ahf[kt], wrr[kt], ar, 0, 0, 0);
            ahh = __builtin_amdgcn_mfma_f32_16x16x32_f16(ahf[kt], whr[kt], ahh, 0, 0, 0);
        }
        // prefetch xm for step l+2 (fire-and-forget; waited at next use)
        if (l + 2 < L_N) LOAD_XM(S, l + 2);
        // gate fully in-register; h never leaves the lane
        float xh[4] = {xh0, xh1, xh2, xh3};
        #pragma unroll
        for (int e = 0; e < 4; ++e) {
            float z = sigmoidf_(az[e]);
            float r = sigmoidf_(ar[e]);
            float c = fmaxf(0.f, fmaf(r, ahh[e], xh[e]));
            float hn = fmaf(z, hreg[e] - c, c);
            hreg[e] = hn;
            A_h[wbuf][m0 + e][hcol] = (_Float16)hn;   // transpose write (b16)
            op[(size_t)e * U_N] = hn;                  // global, fire-and-forget
        }
        op += P_N * U_N;
        BAR();
    };

    for (int l = 0; l < L_N; l += 2) {
        step(l, SA);
        step(l + 1, SB);
    }
}

// ---------------------------------------------- fallback (round-4 kernel) --
struct Acc { f32x4 z, r, xh, hh; };

__global__ __launch_bounds__(NT, 2) void skipgru_mono(
    const float* __restrict__ xg, const float* __restrict__ Wk,
    const float* __restrict__ Wr, const float* __restrict__ bias,
    float* __restrict__ out)
{
    __shared__ __align__(16) _Float16 A_x[2][16][132];
    __shared__ __align__(16) _Float16 A_h[2][16][132];

    const int tid  = threadIdx.x;
    const int lane = tid & 63;
    const int wave = tid >> 6;
    const int ln   = lane & 15;
    const int lg   = lane >> 4;
    const int u    = wave * 16 + ln;
    const int m0   = lg * 4;
    const int b    = blockIdx.x;
    const int hcol = fpos(u);

    const float bz  = bias[u]       + bias[384 + u];
    const float br  = bias[128 + u] + bias[384 + 128 + u];
    const float bxh = bias[256 + u];
    const float brh = bias[384 + 256 + u];

    f16x8 wzk[4], wzr[4], wrk[4], wrr[4], whk[4], whr[4];
    #pragma unroll
    for (int kt = 0; kt < 4; ++kt) {
        #pragma unroll
        for (int e = 0; e < 8; ++e) {
            int k = kt * 32 + ((e >> 2) << 4) + (lg << 2) + (e & 3);
            const float* wkp = Wk + (size_t)k * 384;
            const float* wrp = Wr + (size_t)k * 384;
            wzk[kt][e] = (_Float16)wkp[u];
            wzr[kt][e] = (_Float16)wrp[u];
            wrk[kt][e] = (_Float16)wkp[128 + u];
            wrr[kt][e] = (_Float16)wrp[128 + u];
            whk[kt][e] = (_Float16)wkp[256 + u];
            whr[kt][e] = (_Float16)wrp[256 + u];
        }
    }

    for (int q = tid; q < 16 * 132; q += NT) ((_Float16*)A_h[0])[q] = (_Float16)0;

    const int sm = tid & 15, sc = (tid >> 4) << 2;
    const int scp = fpos(sc);
    const float* xb = xg + (size_t)b * T_N * F_N;
    {
        float4 x0 = *(const float4*)(xb + (size_t)sm * F_N + sc);
        float4 x1 = *(const float4*)(xb + (size_t)(P_N + sm) * F_N + sc);
        f16x4 v0 = {(_Float16)x0.x, (_Float16)x0.y, (_Float16)x0.z, (_Float16)x0.w};
        f16x4 v1 = {(_Float16)x1.x, (_Float16)x1.y, (_Float16)x1.z, (_Float16)x1.w};
        *(f16x4*)&A_x[0][sm][scp] = v0;
        *(f16x4*)&A_x[1][sm][scp] = v1;
    }
    float4 xsB = *(const float4*)(xb + (size_t)(2 * P_N + sm) * F_N + sc);
    float4 xsA = *(const float4*)(xb + (size_t)(3 * P_N + sm) * F_N + sc);

    f32x4 hreg = {0.f, 0.f, 0.f, 0.f};
    float* op = out + ((size_t)b * T_N + m0) * U_N + u;
    __syncthreads();

    Acc P, Q;
    {
        f16x8 axf[4];
        #pragma unroll
        for (int kt = 0; kt < 4; ++kt)
            axf[kt] = *(const f16x8*)&A_x[0][ln][kt * 32 + lg * 8];
        P.z  = {bz, bz, bz, bz};
        P.r  = {br, br, br, br};
        P.xh = {bxh, bxh, bxh, bxh};
        P.hh = {brh, brh, brh, brh};
        #pragma unroll
        for (int kt = 0; kt < 4; ++kt) {
            P.z  = __builtin_amdgcn_mfma_f32_16x16x32_f16(axf[kt], wzk[kt], P.z, 0, 0, 0);
            P.r  = __builtin_amdgcn_mfma_f32_16x16x32_f16(axf[kt], wrk[kt], P.r, 0, 0, 0);
            P.xh = __builtin_amdgcn_mfma_f32_16x16x32_f16(axf[kt], whk[kt], P.xh, 0, 0, 0);
        }
    }

    auto step = [&](int l, float4& xs, Acc& cur, Acc& nxt) {
        const int rbuf = l & 1, wbuf = (l + 1) & 1;
        f16x8 ahf[4];
        #pragma unroll
        for (int kt = 0; kt < 4; ++kt)
            ahf[kt] = *(const f16x8*)&A_h[rbuf][ln][kt * 32 + lg * 8];
        #pragma unroll
        for (int kt = 0; kt < 4; ++kt) {
            cur.z  = __builtin_amdgcn_mfma_f32_16x16x32_f16(ahf[kt], wzr[kt], cur.z, 0, 0, 0);
            cur.r  = __builtin_amdgcn_mfma_f32_16x16x32_f16(ahf[kt], wrr[kt], cur.r, 0, 0, 0);
            cur.hh = __builtin_amdgcn_mfma_f32_16x16x32_f16(ahf[kt], whr[kt], cur.hh, 0, 0, 0);
        }
        if (l + 1 < L_N) {
            f16x8 axf[4];
            #pragma unroll
            for (int kt = 0; kt < 4; ++kt)
                axf[kt] = *(const f16x8*)&A_x[wbuf][ln][kt * 32 + lg * 8];
            nxt.z  = {bz, bz, bz, bz};
            nxt.r  = {br, br, br, br};
            nxt.xh = {bxh, bxh, bxh, bxh};
            nxt.hh = {brh, brh, brh, brh};
            #pragma unroll
            for (int kt = 0; kt < 4; ++kt) {
                nxt.z  = __builtin_amdgcn_mfma_f32_16x16x32_f16(axf[kt], wzk[kt], nxt.z, 0, 0, 0);
                nxt.r  = __builtin_amdgcn_mfma_f32_16x16x32_f16(axf[kt], wrk[kt], nxt.r, 0, 0, 0);
                nxt.xh = __builtin_amdgcn_mfma_f32_16x16x32_f16(axf[kt], whk[kt], nxt.xh, 0, 0, 0);
            }
        }
        #pragma unroll
        for (int e = 0; e < 4; ++e) {
            float z = sigmoidf_(cur.z[e]);
            float r = sigmoidf_(cur.r[e]);
            float c = fmaxf(0.f, fmaf(r, cur.hh[e], cur.xh[e]));
            float hn = fmaf(z, hreg[e] - c, c);
            hreg[e] = hn;
            A_h[wbuf][m0 + e][hcol] = (_Float16)hn;
            op[(size_t)e * U_N] = hn;
        }
        op += P_N * U_N;
        if (l + 2 < L_N) {
            f16x4 v = {(_Float16)xs.x, (_Float16)xs.y, (_Float16)xs.z, (_Float16)xs.w};
            *(f16x4*)&A_x[rbuf][sm][scp] = v;
            if (l + 4 < L_N)
                xs = *(const float4*)(xb + (size_t)((l + 4) * P_N + sm) * F_N + sc);
        }
        BAR();
    };

    for (int l = 0; l < L_N; l += 2) {
        step(l, xsB, P, Q);
        step(l + 1, xsA, Q, P);
    }
}

extern "C" void kernel_launch(void* const* d_in, const int* in_sizes, int n_in,
                              void* d_out, int out_size, void* d_ws, size_t ws_size,
                              hipStream_t stream) {
    const float* inputs = (const float*)d_in[0];
    const float* kernel = (const float*)d_in[1];
    const float* rker   = (const float*)d_in[2];
    const float* bias   = (const float*)d_in[3];
    float* o = (float*)d_out;

    if (ws_size >= WS_NEED) {
        _Float16* xm  = (_Float16*)d_ws;
        _Float16* wkf = (_Float16*)((char*)d_ws + WKF_OFF);
        float*    bc  = (float*)((char*)d_ws + BC_OFF);
        hipLaunchKernelGGL(prep_kernel, dim3(192), dim3(256), 0, stream,
                           kernel, bias, wkf, bc);
        hipLaunchKernelGGL(phase1_kernel, dim3(2048), dim3(256), 0, stream,
                           inputs, wkf, bc, xm);
        hipLaunchKernelGGL(phase2_kernel, dim3(B_N), dim3(NT), 0, stream,
                           rker, bias, xm, o);
    } else {
        hipLaunchKernelGGL(skipgru_mono, dim3(B_N), dim3(NT), 0, stream,
                           inputs, kernel, rker, bias, o);
    }
}